// Round 3
// baseline (448.931 us; speedup 1.0000x reference)
//
#include <hip/hip_runtime.h>

#define DECAYF 0.999f
#define GAINF  0.001f
#define EPSF   1e-6f

// Problem sizes (compile-time): B=512, D=64 dim_codes, K=1024 book, E=64 embed
// out layout: cw[512*4096] | one_hot[512*64*1024] | new_cb[64*1024*64] | new_ema[64*1024]
// NOTE: d_ws is deliberately NOT used (ws_size may be 0 for this problem;
// writing to it is the prime suspect for the prior container crashes).

#define NB 512
#define ND 64
#define NK 1024
#define NE 64

// ---------------- new_codebook pre-init = codebook * DECAY ----------------
__global__ void k_pre_ncb(const float* __restrict__ cb, float* __restrict__ ncb) {
    int f4 = blockIdx.x * blockDim.x + threadIdx.x;   // 1,048,576 float4s
    float4 v = ((const float4*)cb)[f4];
    v.x *= DECAYF; v.y *= DECAYF; v.z *= DECAYF; v.w *= DECAYF;
    ((float4*)ncb)[f4] = v;
}

// ---------------- new_ema pre-init = DECAY * ema ----------------
__global__ void k_pre_nema(const float* __restrict__ ema, float* __restrict__ nema) {
    int i = blockIdx.x * blockDim.x + threadIdx.x;    // 65,536
    nema[i] = DECAYF * ema[i];
}

// ---------------- fused: bsq -> argmin -> one_hot + cw + scatter + ema ----------------
// grid (8 b-chunks, 64 d); block 512 = 64 b-lanes x 8 k-split waves.
// All scratch lives in LDS; atomics land on pre-initialized ncb/nema.
__global__ __launch_bounds__(512) void k_fused(
        const float* __restrict__ x, const float* __restrict__ cb,
        const float* __restrict__ ema,
        float* __restrict__ cw, float* __restrict__ oh,
        float* __restrict__ ncb, float* __restrict__ nema) {
    const int d    = blockIdx.y;
    const int bq   = blockIdx.x;        // b-chunk 0..7
    const int lane = threadIdx.x & 63;  // b within chunk
    const int ks   = threadIdx.x >> 6;  // k-split wave 0..7
    const int t    = threadIdx.x;

    __shared__ float s_bsq[NK];
    __shared__ float s_best[8][64];
    __shared__ int   s_idx[8][64];
    __shared__ int   s_kf[64];
    __shared__ int   s_cnt[NK];

    s_cnt[t] = 0; s_cnt[t + 512] = 0;

    // phase a: b_sq for this d (cooperative, 2 rows/thread)
    const float* cbd = cb + (size_t)d * (NK * NE);
    for (int kk = t; kk < NK; kk += 512) {
        const float4* c4 = (const float4*)(cbd + (size_t)kk * NE);
        float a0 = 0.f, a1 = 0.f, a2 = 0.f, a3 = 0.f;
#pragma unroll
        for (int e4 = 0; e4 < 16; ++e4) {
            float4 v = c4[e4];
            a0 = fmaf(v.x, v.x, a0); a1 = fmaf(v.y, v.y, a1);
            a2 = fmaf(v.z, v.z, a2); a3 = fmaf(v.w, v.w, a3);
        }
        s_bsq[kk] = (a0 + a1) + (a2 + a3);
    }
    __syncthreads();

    // phase b: each thread scans 128 codes with its x-row in registers.
    // dist = b_sq - 2*dot (x_sq is a constant shift per (b,d): argmin-invariant)
    const int b = bq * 64 + lane;
    float4 xr[16];
    const float4* xp4 = (const float4*)(x + (size_t)b * (ND * NE) + d * NE);
#pragma unroll
    for (int e4 = 0; e4 < 16; ++e4) xr[e4] = xp4[e4];

    const float4* c4 = (const float4*)(cbd + (size_t)(ks * 128) * NE);
    float best = 3.4e38f;
    int bestk = ks * 128;
    for (int k = 0; k < 128; ++k) {
        float a0 = 0.f, a1 = 0.f, a2 = 0.f, a3 = 0.f;
#pragma unroll
        for (int e4 = 0; e4 < 16; ++e4) {
            float4 v = c4[k * 16 + e4];
            a0 = fmaf(v.x, xr[e4].x, a0);
            a1 = fmaf(v.y, xr[e4].y, a1);
            a2 = fmaf(v.z, xr[e4].z, a2);
            a3 = fmaf(v.w, xr[e4].w, a3);
        }
        float dot  = (a0 + a1) + (a2 + a3);
        float dist = s_bsq[ks * 128 + k] - 2.0f * dot;
        if (dist < best) { best = dist; bestk = ks * 128 + k; }  // strict <: first index wins
    }
    s_best[ks][lane] = best;
    s_idx[ks][lane]  = bestk;
    __syncthreads();

    // phase c: cross-wave reduce (ascending k-ranges, strict < keeps earliest)
    if (ks == 0) {
#pragma unroll
        for (int j = 1; j < 8; ++j) {
            float ob = s_best[j][lane];
            if (ob < best) { best = ob; bestk = s_idx[j][lane]; }
        }
        s_kf[lane] = bestk;
        atomicAdd(&s_cnt[bestk], 1);   // LDS histogram
    }
    __syncthreads();

    // phase d: one-hot rows. Wave ks owns rows ks*8..ks*8+7; 1 KiB contiguous per store-iter.
    for (int rr = 0; rr < 8; ++rr) {
        int r  = ks * 8 + rr;
        int kk = s_kf[r];
        float* orow = oh + (size_t)(bq * 64 + r) * (ND * NK) + d * NK;
#pragma unroll
        for (int j = 0; j < 4; ++j) {
            int k0 = j * 256 + lane * 4;
            float4 o;
            o.x = (k0     == kk) ? 1.f : 0.f;
            o.y = (k0 + 1 == kk) ? 1.f : 0.f;
            o.z = (k0 + 2 == kk) ? 1.f : 0.f;
            o.w = (k0 + 3 == kk) ? 1.f : 0.f;
            *(float4*)(orow + k0) = o;
        }
    }

    // phase e+f: cw rows (exact reference arithmetic x+(c-x)) + scatter into ncb
    for (int rr = 0; rr < 8; ++rr) {
        int r  = ks * 8 + rr;
        int kk = s_kf[r];
        int br = bq * 64 + r;
        float xv = x[(size_t)br * (ND * NE) + d * NE + lane];
        float cv = cbd[(size_t)kk * NE + lane];
        cw[(size_t)br * (ND * NE) + d * NE + lane] = xv + (cv - xv);
        float scale = GAINF / (ema[d * NK + kk] + EPSF);
        atomicAdd(&ncb[(size_t)d * (NK * NE) + (size_t)kk * NE + lane], scale * xv);
    }

    // phase g: flush histogram into nema (<= 8 blocks collide per bin)
    for (int kk = t; kk < NK; kk += 512) {
        int c = s_cnt[kk];
        if (c) atomicAdd(&nema[d * NK + kk], GAINF * (float)c);
    }
}

extern "C" void kernel_launch(void* const* d_in, const int* in_sizes, int n_in,
                              void* d_out, int out_size, void* d_ws, size_t ws_size,
                              hipStream_t stream) {
    const float* x   = (const float*)d_in[0];   // [512,4096]
    const float* cb  = (const float*)d_in[1];   // [64,1024,64]
    const float* ema = (const float*)d_in[2];   // [64,1024]

    float* out  = (float*)d_out;
    float* cw   = out;                          // 2,097,152
    float* oh   = out + 2097152;                // 33,554,432
    float* ncb  = out + 2097152 + 33554432;     // 4,194,304
    float* nema = ncb + 4194304;                // 65,536

    k_pre_ncb<<<4096, 256, 0, stream>>>(cb, ncb);
    k_pre_nema<<<256, 256, 0, stream>>>(ema, nema);

    dim3 g_fused(8, 64);
    k_fused<<<g_fused, 512, 0, stream>>>(x, cb, ema, cw, oh, ncb, nema);
}

// Round 5
// 429.936 us; speedup vs baseline: 1.0442x; 1.0442x over previous
//
#include <hip/hip_runtime.h>

#define DECAYF 0.999f
#define GAINF  0.001f
#define EPSF   1e-6f

// Problem sizes (compile-time): B=512, D=64 dim_codes, K=1024 book, E=64 embed
// out layout: cw[512*4096] | one_hot[512*64*1024] | new_cb[64*1024*64] | new_ema[64*1024]
// d_ws deliberately unused.

#define NB 512
#define ND 64
#define NK 1024
#define NE 64

// ---------------- pre-init: ncb = cb*DECAY (1,048,576 f4) ; nema = ema*DECAY (16,384 f4) ----
__global__ void k_pre(const float* __restrict__ cb, const float* __restrict__ ema,
                      float* __restrict__ ncb, float* __restrict__ nema) {
    int i = blockIdx.x * blockDim.x + threadIdx.x;   // 1,064,960 float4s total
    if (i < 1048576) {
        float4 v = ((const float4*)cb)[i];
        v.x *= DECAYF; v.y *= DECAYF; v.z *= DECAYF; v.w *= DECAYF;
        ((float4*)ncb)[i] = v;
    } else {
        int j = i - 1048576;
        float4 v = ((const float4*)ema)[j];
        v.x *= DECAYF; v.y *= DECAYF; v.z *= DECAYF; v.w *= DECAYF;
        ((float4*)nema)[j] = v;
    }
}

// ---------------- fused: bsq -> argmin -> one_hot + cw + scatter + ema ----------------
// grid (64 d, 8 bq)  [d on x so the 8 blocks sharing a codebook d-slice map to
// the same XCD: linear_id % 8 == d % 8 -> one 256KB slice fetched once per XCD L2]
// block 512 = 64 b-lanes x 8 k-split waves.
// __launch_bounds__(512,4): 4 waves/EU -> VGPR budget 128 so the 64-float x row
// stays IN REGISTERS (round-3 kernel had VGPR_Count=60 -> x spilled/reloaded
// every k-iteration; that was the 314us).
__global__ __launch_bounds__(512, 4) void k_fused(
        const float* __restrict__ x, const float* __restrict__ cb,
        const float* __restrict__ ema,
        float* __restrict__ cw, float* __restrict__ oh,
        float* __restrict__ ncb, float* __restrict__ nema) {
    const int d    = blockIdx.x;
    const int bq   = blockIdx.y;        // b-chunk 0..7
    const int lane = threadIdx.x & 63;  // b within chunk
    const int ks   = threadIdx.x >> 6;  // k-split wave 0..7
    const int t    = threadIdx.x;

    __shared__ float s_bsq[NK];
    __shared__ float s_best[8][64];
    __shared__ int   s_idx[8][64];
    __shared__ int   s_kf[64];
    __shared__ int   s_cnt[NK];

    s_cnt[t] = 0; s_cnt[t + 512] = 0;

    // phase a: b_sq for this d (cooperative, 2 rows/thread)
    const float* cbd = cb + (size_t)d * (NK * NE);
    for (int kk = t; kk < NK; kk += 512) {
        const float4* c4a = (const float4*)(cbd + (size_t)kk * NE);
        float a0 = 0.f, a1 = 0.f, a2 = 0.f, a3 = 0.f;
#pragma unroll
        for (int e4 = 0; e4 < 16; ++e4) {
            float4 v = c4a[e4];
            a0 = fmaf(v.x, v.x, a0); a1 = fmaf(v.y, v.y, a1);
            a2 = fmaf(v.z, v.z, a2); a3 = fmaf(v.w, v.w, a3);
        }
        s_bsq[kk] = (a0 + a1) + (a2 + a3);
    }
    __syncthreads();

    // phase b: each thread scans 128 codes, x-row in registers.
    // dist = b_sq - 2*dot (x_sq is a constant shift per (b,d): argmin-invariant)
    const int b = bq * 64 + lane;
    float4 xr[16];
    const float4* xp4 = (const float4*)(x + (size_t)b * (ND * NE) + d * NE);
#pragma unroll
    for (int e4 = 0; e4 < 16; ++e4) xr[e4] = xp4[e4];

    const float4* c4 = (const float4*)(cbd + (size_t)(ks * 128) * NE);
    float best = 3.4e38f;
    int bestk = ks * 128;
    for (int k = 0; k < 128; ++k) {
        float a0 = 0.f, a1 = 0.f, a2 = 0.f, a3 = 0.f;
#pragma unroll
        for (int e4 = 0; e4 < 16; ++e4) {
            float4 v = c4[e4];                       // wave-uniform addr -> L1 broadcast
            a0 = fmaf(v.x, xr[e4].x, a0);
            a1 = fmaf(v.y, xr[e4].y, a1);
            a2 = fmaf(v.z, xr[e4].z, a2);
            a3 = fmaf(v.w, xr[e4].w, a3);
        }
        c4 += 16;
        float dot  = (a0 + a1) + (a2 + a3);
        float dist = s_bsq[ks * 128 + k] - 2.0f * dot;
        if (dist < best) { best = dist; bestk = ks * 128 + k; }  // strict <: first index wins
    }
    s_best[ks][lane] = best;
    s_idx[ks][lane]  = bestk;
    __syncthreads();

    // phase c: cross-wave reduce (ascending k-ranges, strict < keeps earliest)
    if (ks == 0) {
#pragma unroll
        for (int j = 1; j < 8; ++j) {
            float ob = s_best[j][lane];
            if (ob < best) { best = ob; bestk = s_idx[j][lane]; }
        }
        s_kf[lane] = bestk;
        atomicAdd(&s_cnt[bestk], 1);   // LDS histogram
    }
    __syncthreads();

    // phase d: one-hot rows. Wave ks owns rows ks*8..ks*8+7; 4KB contiguous per row.
    for (int rr = 0; rr < 8; ++rr) {
        int r  = ks * 8 + rr;
        int kk = s_kf[r];
        float* orow = oh + (size_t)(bq * 64 + r) * (ND * NK) + d * NK;
#pragma unroll
        for (int j = 0; j < 4; ++j) {
            int k0 = j * 256 + lane * 4;
            float4 o;
            o.x = (k0     == kk) ? 1.f : 0.f;
            o.y = (k0 + 1 == kk) ? 1.f : 0.f;
            o.z = (k0 + 2 == kk) ? 1.f : 0.f;
            o.w = (k0 + 3 == kk) ? 1.f : 0.f;
            *(float4*)(orow + k0) = o;
        }
    }

    // phase e+f: cw rows (exact reference arithmetic x+(c-x)) + scatter into ncb
    for (int rr = 0; rr < 8; ++rr) {
        int r  = ks * 8 + rr;
        int kk = s_kf[r];
        int br = bq * 64 + r;
        float xv = x[(size_t)br * (ND * NE) + d * NE + lane];
        float cv = cbd[(size_t)kk * NE + lane];
        cw[(size_t)br * (ND * NE) + d * NE + lane] = xv + (cv - xv);
        float scale = GAINF / (ema[d * NK + kk] + EPSF);
        atomicAdd(&ncb[(size_t)d * (NK * NE) + (size_t)kk * NE + lane], scale * xv);
    }

    // phase g: flush histogram into nema (<= 8 blocks collide per bin)
    for (int kk = t; kk < NK; kk += 512) {
        int c = s_cnt[kk];
        if (c) atomicAdd(&nema[d * NK + kk], GAINF * (float)c);
    }
}

extern "C" void kernel_launch(void* const* d_in, const int* in_sizes, int n_in,
                              void* d_out, int out_size, void* d_ws, size_t ws_size,
                              hipStream_t stream) {
    const float* x   = (const float*)d_in[0];   // [512,4096]
    const float* cb  = (const float*)d_in[1];   // [64,1024,64]
    const float* ema = (const float*)d_in[2];   // [64,1024]

    float* out  = (float*)d_out;
    float* cw   = out;                          // 2,097,152
    float* oh   = out + 2097152;                // 33,554,432
    float* ncb  = out + 2097152 + 33554432;     // 4,194,304
    float* nema = ncb + 4194304;                // 65,536

    k_pre<<<4160, 256, 0, stream>>>(cb, ema, ncb, nema);

    dim3 g_fused(64, 8);                        // d on x -> XCD-aligned codebook reuse
    k_fused<<<g_fused, 512, 0, stream>>>(x, cb, ema, cw, oh, ncb, nema);
}

// Round 6
// 418.703 us; speedup vs baseline: 1.0722x; 1.0268x over previous
//
#include <hip/hip_runtime.h>

#define DECAYF 0.999f
#define GAINF  0.001f
#define EPSF   1e-6f

// Problem sizes (compile-time): B=512, D=64 dim_codes, K=1024 book, E=64 embed
// out layout: cw[512*4096] | one_hot[512*64*1024] | new_cb[64*1024*64] | new_ema[64*1024]
// d_ws deliberately unused.

#define NB 512
#define ND 64
#define NK 1024
#define NE 64

// ---------------- pre-init: ncb = cb*DECAY ; nema = ema*DECAY ----------------
__global__ void k_pre(const float* __restrict__ cb, const float* __restrict__ ema,
                      float* __restrict__ ncb, float* __restrict__ nema) {
    int i = blockIdx.x * blockDim.x + threadIdx.x;   // 1,064,960 float4s total
    if (i < 1048576) {
        float4 v = ((const float4*)cb)[i];
        v.x *= DECAYF; v.y *= DECAYF; v.z *= DECAYF; v.w *= DECAYF;
        ((float4*)ncb)[i] = v;
    } else {
        int j = i - 1048576;
        float4 v = ((const float4*)ema)[j];
        v.x *= DECAYF; v.y *= DECAYF; v.z *= DECAYF; v.w *= DECAYF;
        ((float4*)nema)[j] = v;
    }
}

// ---------------- fused: bsq -> argmin -> one_hot + cw + scatter + ema ----------------
// grid (64 d, 8 bq): d%8 fixes the XCD so the 8 bq-blocks sharing a codebook
// d-slice hit one L2 (round-5: FETCH 143->20 MB, keep).
// block 512 = 8 waves. SCAN RESTRUCTURE (round-5 post-mortem): wave = 32 b x 2
// e-halves; each thread holds 32 x-floats (8 f4 = 32 VGPR) and scans 256 k,
// combining half-dots with one shfl_xor(32). Live state fits the allocator's
// 60-VGPR target, so x stays in registers (round-5: x reloaded from L1 every
// k-iter at VGPR_Count=60 -> 300us, VALUBusy 28%).
__global__ __launch_bounds__(512) void k_fused(
        const float* __restrict__ x, const float* __restrict__ cb,
        const float* __restrict__ ema,
        float* __restrict__ cw, float* __restrict__ oh,
        float* __restrict__ ncb, float* __restrict__ nema) {
    const int d    = blockIdx.x;
    const int bq   = blockIdx.y;        // b-chunk 0..7
    const int t    = threadIdx.x;
    const int lane = t & 63;
    const int w    = t >> 6;            // wave 0..7
    const int bh   = w >> 2;            // b-half 0/1
    const int ks   = w & 3;             // k-quarter 0..3 (256 codes each)
    const int h    = lane >> 5;         // e-half 0/1
    const int bb   = lane & 31;         // b within half

    __shared__ float s_bsq[NK];
    __shared__ float s_best[4][64];
    __shared__ int   s_idx[4][64];
    __shared__ int   s_kf[64];
    __shared__ int   s_cnt[NK];

    s_cnt[t] = 0; s_cnt[t + 512] = 0;

    // phase a: b_sq for this d (cooperative, 2 rows/thread)
    const float* cbd = cb + (size_t)d * (NK * NE);
    for (int kk = t; kk < NK; kk += 512) {
        const float4* c4a = (const float4*)(cbd + (size_t)kk * NE);
        float a0 = 0.f, a1 = 0.f, a2 = 0.f, a3 = 0.f;
#pragma unroll
        for (int e4 = 0; e4 < 16; ++e4) {
            float4 v = c4a[e4];
            a0 = fmaf(v.x, v.x, a0); a1 = fmaf(v.y, v.y, a1);
            a2 = fmaf(v.z, v.z, a2); a3 = fmaf(v.w, v.w, a3);
        }
        s_bsq[kk] = (a0 + a1) + (a2 + a3);
    }
    __syncthreads();

    // phase b: scan 256 codes; x half-row (32 floats) in registers.
    // dist = b_sq - 2*dot (x_sq is a constant shift per (b,d): argmin-invariant)
    const int bl = bh * 32 + bb;        // b_local 0..63
    const int b  = bq * 64 + bl;
    float4 xr[8];
    const float4* xp4 = (const float4*)(x + (size_t)b * (ND * NE) + d * NE + h * 32);
#pragma unroll
    for (int e4 = 0; e4 < 8; ++e4) xr[e4] = xp4[e4];

    const float4* c4   = (const float4*)(cbd + (size_t)(ks * 256) * NE + h * 32);
    const float*  bsqw = s_bsq + ks * 256;
    float best  = 3.4e38f;
    int   bestk = ks * 256;
    for (int k = 0; k < 256; ++k) {
        float a0 = 0.f, a1 = 0.f, a2 = 0.f, a3 = 0.f;
#pragma unroll
        for (int e4 = 0; e4 < 8; ++e4) {
            float4 v = c4[e4];                   // half-wave-uniform addr -> broadcast
            a0 = fmaf(v.x, xr[e4].x, a0);
            a1 = fmaf(v.y, xr[e4].y, a1);
            a2 = fmaf(v.z, xr[e4].z, a2);
            a3 = fmaf(v.w, xr[e4].w, a3);
        }
        c4 += 16;                                // next code row (64 floats)
        float half = (a0 + a1) + (a2 + a3);
        float dot  = half + __shfl_xor(half, 32, 64);   // both halves: bit-identical
        float dist = bsqw[k] - 2.0f * dot;
        if (dist < best) { best = dist; bestk = ks * 256 + k; }  // strict <: first idx wins
    }
    if (h == 0) { s_best[ks][bl] = best; s_idx[ks][bl] = bestk; }
    __syncthreads();

    // phase c: per-b reduce over the 4 ascending k-quarters (strict < keeps earliest)
    if (t < 64) {
        float bv = s_best[0][t];
        int   bk = s_idx[0][t];
#pragma unroll
        for (int j = 1; j < 4; ++j) {
            float ob = s_best[j][t];
            if (ob < bv) { bv = ob; bk = s_idx[j][t]; }
        }
        s_kf[t] = bk;
        atomicAdd(&s_cnt[bk], 1);    // LDS histogram
    }
    __syncthreads();

    // phase d: one-hot rows. Wave w owns rows w*8..w*8+7; 4KB contiguous per row.
    for (int rr = 0; rr < 8; ++rr) {
        int r  = w * 8 + rr;
        int kk = s_kf[r];
        float* orow = oh + (size_t)(bq * 64 + r) * (ND * NK) + d * NK;
#pragma unroll
        for (int j = 0; j < 4; ++j) {
            int k0 = j * 256 + lane * 4;
            float4 o;
            o.x = (k0     == kk) ? 1.f : 0.f;
            o.y = (k0 + 1 == kk) ? 1.f : 0.f;
            o.z = (k0 + 2 == kk) ? 1.f : 0.f;
            o.w = (k0 + 3 == kk) ? 1.f : 0.f;
            *(float4*)(orow + k0) = o;
        }
    }

    // phase e+f: cw rows (exact reference arithmetic x+(c-x)) + scatter into ncb
    for (int rr = 0; rr < 8; ++rr) {
        int r  = w * 8 + rr;
        int kk = s_kf[r];
        int br = bq * 64 + r;
        float xv = x[(size_t)br * (ND * NE) + d * NE + lane];
        float cv = cbd[(size_t)kk * NE + lane];
        cw[(size_t)br * (ND * NE) + d * NE + lane] = xv + (cv - xv);
        float scale = GAINF / (ema[d * NK + kk] + EPSF);
        atomicAdd(&ncb[(size_t)d * (NK * NE) + (size_t)kk * NE + lane], scale * xv);
    }

    // phase g: flush histogram into nema (<= 8 blocks collide per bin)
    for (int kk = t; kk < NK; kk += 512) {
        int c = s_cnt[kk];
        if (c) atomicAdd(&nema[d * NK + kk], GAINF * (float)c);
    }
}

extern "C" void kernel_launch(void* const* d_in, const int* in_sizes, int n_in,
                              void* d_out, int out_size, void* d_ws, size_t ws_size,
                              hipStream_t stream) {
    const float* x   = (const float*)d_in[0];   // [512,4096]
    const float* cb  = (const float*)d_in[1];   // [64,1024,64]
    const float* ema = (const float*)d_in[2];   // [64,1024]

    float* out  = (float*)d_out;
    float* cw   = out;                          // 2,097,152
    float* oh   = out + 2097152;                // 33,554,432
    float* ncb  = out + 2097152 + 33554432;     // 4,194,304
    float* nema = ncb + 4194304;                // 65,536

    k_pre<<<4160, 256, 0, stream>>>(cb, ema, ncb, nema);

    dim3 g_fused(64, 8);                        // d on x -> XCD-aligned codebook reuse
    k_fused<<<g_fused, 512, 0, stream>>>(x, cb, ema, cw, oh, ncb, nema);
}